// Round 6
// baseline (72.621 us; speedup 1.0000x reference)
//
#include <hip/hip_runtime.h>
#include <math.h>

#define NB 384          // batch size B
#define ND4 64          // D/4 = 256/4
#define NW 6            // waves per block (384 threads)
#define TMARGIN 0.3f

// Two anchors per block (grid=192, 384 threads, 6 waves): each embedding row is
// loaded ONCE and used for both anchors' dist rows (halves L2 traffic vs 1
// anchor/block, and 192 blocks <= 256 CUs removes the 1.5 block/CU imbalance).
// Phase 2/3 split by wave-group: waves 0-2 -> anchor 2b, waves 3-5 -> 2b+1.
// Per-anchor partials stored plain (no global atomics); 1-wave final reduces.
__global__ __launch_bounds__(NB) void triplet_main(
    const float4* __restrict__ E4, const int* __restrict__ labels,
    float* __restrict__ ws_loss, float* __restrict__ ws_cnt)
{
    const int b = blockIdx.x;
    const int a0 = 2 * b;
    const int t = threadIdx.x;
    const int w = t >> 6;     // wave id 0..5
    const int l = t & 63;     // lane id
    const int s = l & 7;      // sub-lane within 8-lane row group
    const int g = l >> 3;     // row group 0..7

    __shared__ float4 sa4[2][ND4];   // both anchor embeddings (2 KB)
    __shared__ float  sdist[2][NB];  // dist rows for both anchors (3 KB)
    __shared__ int    slabel[NB];
    __shared__ int    spos[2][NB];   // positive index lists
    __shared__ int    scount[2];
    __shared__ float  swred[NW];
    __shared__ float  snegmin[2];

    if (t < 2) scount[t] = 0;
    if (t < ND4)            sa4[0][t]       = E4[a0 * ND4 + t];
    else if (t < 2 * ND4)   sa4[1][t - ND4] = E4[(a0 + 1) * ND4 + (t - ND4)];
    slabel[t] = labels[t];
    __syncthreads();

    // anchor float4s this sub-lane needs (LDS broadcast reads)
    float4 u0[8], u1[8];
    #pragma unroll
    for (int j = 0; j < 8; ++j) { u0[j] = sa4[0][s + (j << 3)]; u1[j] = sa4[1][s + (j << 3)]; }

    // ---- phase 1: wave w computes rows [64w,64w+64) for BOTH anchors ----
    #pragma unroll
    for (int i = 0; i < 8; ++i) {
        const int row = (w << 6) + (i << 3) + g;
        const float4* __restrict__ p = E4 + row * ND4 + s;
        float d0 = 0.f, d1 = 0.f;
        #pragma unroll
        for (int j = 0; j < 8; ++j) {
            float4 v = p[j << 3];                    // lanes 0-7 cover 128B of row
            float x0 = v.x - u0[j].x, y0 = v.y - u0[j].y, z0 = v.z - u0[j].z, q0 = v.w - u0[j].w;
            d0 += x0*x0 + y0*y0 + z0*z0 + q0*q0;
            float x1 = v.x - u1[j].x, y1 = v.y - u1[j].y, z1 = v.z - u1[j].z, q1 = v.w - u1[j].w;
            d1 += x1*x1 + y1*y1 + z1*z1 + q1*q1;
        }
        d0 += __shfl_xor(d0, 1, 64); d1 += __shfl_xor(d1, 1, 64);
        d0 += __shfl_xor(d0, 2, 64); d1 += __shfl_xor(d1, 2, 64);
        d0 += __shfl_xor(d0, 4, 64); d1 += __shfl_xor(d1, 4, 64);
        if (s == 0) { sdist[0][row] = d0; sdist[1][row] = d1; }
    }
    __syncthreads();

    // ---- wave-group split: waves 0-2 handle anchor a0, waves 3-5 handle a0+1
    const int ai = (w >= 3) ? 1 : 0;
    const int wl = w - 3 * ai;            // 0..2 within group
    const int aa = a0 + ai;
    const int la = slabel[aa];

    // ---- phase 2: negmin (2 cols/lane) + positive collection ----
    {
        const int c0 = wl * 128 + l, c1 = c0 + 64;
        const int lb0 = slabel[c0], lb1 = slabel[c1];
        float nm = fminf((lb0 != la) ? sdist[ai][c0] : INFINITY,
                         (lb1 != la) ? sdist[ai][c1] : INFINITY);
        #pragma unroll
        for (int off = 32; off > 0; off >>= 1)
            nm = fminf(nm, __shfl_xor(nm, off, 64));
        if (l == 0) swred[w] = nm;
        if (lb0 == la && c0 != aa) spos[ai][atomicAdd(&scount[ai], 1)] = c0;
        if (lb1 == la && c1 != aa) spos[ai][atomicAdd(&scount[ai], 1)] = c1;
    }
    __syncthreads();
    if (t < 2)
        snegmin[t] = fminf(fminf(swred[3 * t], swred[3 * t + 1]), swred[3 * t + 2]);
    __syncthreads();

    const float negmin  = snegmin[ai];
    const int   P       = scount[ai];
    const bool  has_neg = (negmin < INFINITY);

    // ---- phase 3: semi-hard mining, positives strided over 3 waves ----
    float lsum = 0.f;
    if (has_neg) {
        for (int pi = wl; pi < P; pi += 3) {
            const int   p  = spos[ai][pi];
            const float dp = sdist[ai][p];
            const float hi = dp + TMARGIN;
            float m = INFINITY;
            #pragma unroll
            for (int i = 0; i < NB / 64; ++i) {
                const int   n  = (i << 6) + l;
                const float dn = sdist[ai][n];
                if ((slabel[n] != la) && (dn > dp) && (dn < hi))
                    m = fminf(m, dn);
            }
            #pragma unroll
            for (int off = 32; off > 0; off >>= 1)
                m = fminf(m, __shfl_xor(m, off, 64));
            if (l == 0) {
                const float dan = (m < INFINITY) ? m : negmin;
                lsum += fmaxf(dp - dan + TMARGIN, 0.f);
            }
        }
    }

    // ---- per-anchor reduce; plain stores (no global atomics) ----
    __syncthreads();               // protect swred reuse
    if (l == 0) swred[w] = lsum;
    __syncthreads();
    if (t < 2) {
        const float ssum = swred[3 * t] + swred[3 * t + 1] + swred[3 * t + 2];
        ws_loss[a0 + t] = ssum;
        ws_cnt[a0 + t]  = (snegmin[t] < INFINITY) ? (float)scount[t] : 0.f;
    }
}

// Single-wave finalize: 64 lanes x 6 strided elements, shuffle reduce, 1 store.
__global__ __launch_bounds__(64) void triplet_final(
    const float* __restrict__ ws_loss, const float* __restrict__ ws_cnt,
    float* __restrict__ out)
{
    const int l = threadIdx.x;
    float s = 0.f, c = 0.f;
    #pragma unroll
    for (int i = 0; i < NB / 64; ++i) {
        s += ws_loss[(i << 6) + l];
        c += ws_cnt [(i << 6) + l];
    }
    #pragma unroll
    for (int off = 32; off > 0; off >>= 1) {
        s += __shfl_xor(s, off, 64);
        c += __shfl_xor(c, off, 64);
    }
    if (l == 0) out[0] = s / fmaxf(c, 1.f);
}

extern "C" void kernel_launch(void* const* d_in, const int* in_sizes, int n_in,
                              void* d_out, int out_size, void* d_ws, size_t ws_size,
                              hipStream_t stream) {
    const float4* emb  = (const float4*)d_in[0];   // (384, 256) fp32
    const int* labels  = (const int*)d_in[1];      // (384,) int32
    float* out = (float*)d_out;

    float* ws_loss = (float*)d_ws;
    float* ws_cnt  = ws_loss + NB;

    triplet_main<<<NB / 2, NB, 0, stream>>>(emb, labels, ws_loss, ws_cnt);
    triplet_final<<<1, 64, 0, stream>>>(ws_loss, ws_cnt, out);
}

// Round 7
// 65.764 us; speedup vs baseline: 1.1043x; 1.1043x over previous
//
#include <hip/hip_runtime.h>
#include <math.h>

#define NB 384          // batch size B
#define ND4 64          // D/4 = 256/4
#define NW 6            // waves per block (384 threads)
#define TMARGIN 0.3f

// One block per anchor (384 blocks x 384 threads, 6 waves) — R5 structure,
// which A/B-proved best: 2304 resident waves hide L2 latency (R6's 192-block
// variant halved waves and regressed +7us). Anchor fragment comes from global
// broadcast loads (8x-replicated 128B segments) so phase 1 needs NO entry
// barrier. Plain per-block stores (no device atomics/fences — R3/R5 A/B showed
// cross-XCD release fences cost ~12us); 1-wave final kernel reduces.
__global__ __launch_bounds__(NB) void triplet_main(
    const float4* __restrict__ E4, const int* __restrict__ labels,
    float* __restrict__ ws_loss, float* __restrict__ ws_cnt)
{
    const int a = blockIdx.x;
    const int t = threadIdx.x;
    const int w = t >> 6;     // wave id 0..5
    const int l = t & 63;     // lane id
    const int s = l & 7;      // sub-lane within 8-lane row group
    const int g = l >> 3;     // row group 0..7

    __shared__ float  sdist[NB];   // dist[a][:]
    __shared__ int    slabel[NB];
    __shared__ int    spos[NB];    // positive indices
    __shared__ int    scount;
    __shared__ float  swred[NW];
    __shared__ float  snegmin;

    if (t == 0) scount = 0;
    slabel[t] = labels[t];         // visible after the post-phase-1 barrier

    // anchor float4s this sub-lane needs: global broadcast loads, no barrier
    float4 u[8];
    #pragma unroll
    for (int j = 0; j < 8; ++j) u[j] = E4[a * ND4 + s + (j << 3)];

    // ---- phase 1: wave w computes rows [64w, 64w+64), 8 rows per iter ----
    #pragma unroll
    for (int i = 0; i < 8; ++i) {
        const int row = (w << 6) + (i << 3) + g;
        const float4* __restrict__ p = E4 + row * ND4 + s;
        float d = 0.f;
        #pragma unroll
        for (int j = 0; j < 8; ++j) {
            float4 v = p[j << 3];                      // lanes 0-7 cover 128B of row
            float dx = v.x - u[j].x, dy = v.y - u[j].y;
            float dz = v.z - u[j].z, dq = v.w - u[j].w;
            d += dx*dx + dy*dy + dz*dz + dq*dq;
        }
        d += __shfl_xor(d, 1, 64);                     // reduce within 8-lane group
        d += __shfl_xor(d, 2, 64);
        d += __shfl_xor(d, 4, 64);
        if (s == 0) sdist[row] = d;
    }
    __syncthreads();

    const int la = slabel[a];

    // ---- phase 2: negmin over row + collect positives ----
    float nm = (slabel[t] != la) ? sdist[t] : INFINITY;
    #pragma unroll
    for (int off = 32; off > 0; off >>= 1)
        nm = fminf(nm, __shfl_xor(nm, off, 64));
    if (l == 0) swred[w] = nm;
    if (slabel[t] == la && t != a) {
        int idx = atomicAdd(&scount, 1);
        spos[idx] = t;
    }
    __syncthreads();
    if (t == 0) {
        float m = swred[0];
        #pragma unroll
        for (int i = 1; i < NW; ++i) m = fminf(m, swred[i]);
        snegmin = m;
    }
    __syncthreads();

    const float negmin  = snegmin;
    const int   P       = scount;
    const bool  has_neg = (negmin < INFINITY);

    // ---- phase 3: semi-hard mining, one positive per wave ----
    float lsum = 0.f;
    if (has_neg) {
        for (int pi = w; pi < P; pi += NW) {
            const int   p  = spos[pi];
            const float dp = sdist[p];
            const float hi = dp + TMARGIN;
            float m = INFINITY;
            #pragma unroll
            for (int i = 0; i < NB / 64; ++i) {
                const int   n  = (i << 6) + l;
                const float dn = sdist[n];
                if ((slabel[n] != la) && (dn > dp) && (dn < hi))
                    m = fminf(m, dn);
            }
            #pragma unroll
            for (int off = 32; off > 0; off >>= 1)
                m = fminf(m, __shfl_xor(m, off, 64));
            if (l == 0) {
                const float dan = (m < INFINITY) ? m : negmin;
                lsum += fmaxf(dp - dan + TMARGIN, 0.f);
            }
        }
    }

    // ---- block reduce; plain per-block stores (no atomics) ----
    __syncthreads();               // protect swred reuse
    if (l == 0) swred[w] = lsum;
    __syncthreads();
    if (t == 0) {
        float ssum = swred[0];
        #pragma unroll
        for (int i = 1; i < NW; ++i) ssum += swred[i];
        ws_loss[a] = ssum;
        ws_cnt[a]  = has_neg ? (float)P : 0.f;
    }
}

// Single-wave finalize: 64 lanes x 6 strided elements, shuffle reduce, 1 store.
__global__ __launch_bounds__(64) void triplet_final(
    const float* __restrict__ ws_loss, const float* __restrict__ ws_cnt,
    float* __restrict__ out)
{
    const int l = threadIdx.x;
    float s = 0.f, c = 0.f;
    #pragma unroll
    for (int i = 0; i < NB / 64; ++i) {
        s += ws_loss[(i << 6) + l];
        c += ws_cnt [(i << 6) + l];
    }
    #pragma unroll
    for (int off = 32; off > 0; off >>= 1) {
        s += __shfl_xor(s, off, 64);
        c += __shfl_xor(c, off, 64);
    }
    if (l == 0) out[0] = s / fmaxf(c, 1.f);
}

extern "C" void kernel_launch(void* const* d_in, const int* in_sizes, int n_in,
                              void* d_out, int out_size, void* d_ws, size_t ws_size,
                              hipStream_t stream) {
    const float4* emb  = (const float4*)d_in[0];   // (384, 256) fp32
    const int* labels  = (const int*)d_in[1];      // (384,) int32
    float* out = (float*)d_out;

    float* ws_loss = (float*)d_ws;
    float* ws_cnt  = ws_loss + NB;

    triplet_main<<<NB, NB, 0, stream>>>(emb, labels, ws_loss, ws_cnt);
    triplet_final<<<1, 64, 0, stream>>>(ws_loss, ws_cnt, out);
}